// Round 12
// baseline (309.151 us; speedup 1.0000x reference)
//
#include <hip/hip_runtime.h>
#include <hip/hip_bf16.h>
#include <math.h>

#define N_NODES 20000
#define N_EDGES 640000
#define F_IN 128
#define HID 64
#define HEADS 4
#define HC 256      // HEADS*HID
#define OUT_DIM 10
#define NUM_GRAPHS 128
#define NEG_SLOPE 0.2f
#define BN_EPS 1e-5f
#define CONV_N (N_NODES * F_IN / 4)
#define ELL_CAP 128   // max degree+1; deg ~ Poisson(32), P(deg>=128) < 1e-30

typedef short bf16s;
typedef unsigned short u16;
using bf16x8 = __attribute__((ext_vector_type(8))) short;
using bf16x4 = __attribute__((ext_vector_type(4))) short;
using f32x4 = __attribute__((ext_vector_type(4))) float;

__device__ __forceinline__ float bs2f(short s) {
    unsigned int u = ((unsigned int)(unsigned short)s) << 16;
    return __builtin_bit_cast(float, u);
}
__device__ __forceinline__ short f2bs(float f) {
    unsigned int u = __builtin_bit_cast(unsigned int, f);
    unsigned int r = u + 0x7FFFu + ((u >> 16) & 1u);
    return (short)(r >> 16);
}

// ---- fused prep: x->bf16, 3x W transpose, cnt=1 + self-loop slot, colstats=0, counter=0 ----

__global__ void prep_all(const float* __restrict__ x, bf16s* __restrict__ xb,
                         const float* __restrict__ W1, const float* __restrict__ W2,
                         const float* __restrict__ W3,
                         bf16s* __restrict__ Wt1, bf16s* __restrict__ Wt2,
                         bf16s* __restrict__ Wt3,
                         int* __restrict__ cnt, u16* __restrict__ ell,
                         float* __restrict__ colstats, int* __restrict__ counter) {
    int tid = blockIdx.x * blockDim.x + threadIdx.x;
    if (tid < CONV_N) {
        float4 v = reinterpret_cast<const float4*>(x)[tid];
        bf16x4 o;
        o[0] = f2bs(v.x); o[1] = f2bs(v.y); o[2] = f2bs(v.z); o[3] = f2bs(v.w);
        reinterpret_cast<bf16x4*>(xb)[tid] = o;
        return;
    }
    tid -= CONV_N;
    if (tid < HC * F_IN) { int c = tid >> 7, k = tid & 127; Wt1[tid] = f2bs(W1[(size_t)k * HC + c]); return; }
    tid -= HC * F_IN;
    if (tid < HC * HC) { int c = tid >> 8, k = tid & 255; Wt2[tid] = f2bs(W2[(size_t)k * HC + c]); return; }
    tid -= HC * HC;
    if (tid < HC * HC) { int c = tid >> 8, k = tid & 255; Wt3[tid] = f2bs(W3[(size_t)k * HC + c]); return; }
    tid -= HC * HC;
    if (tid < N_NODES) {   // self-loop pre-planted at slot 0
        cnt[tid] = 1;
        ell[(size_t)tid * ELL_CAP] = (u16)tid;
        return;
    }
    tid -= N_NODES;
    if (tid < 2 * HC) { colstats[tid] = 0.f; return; }
    tid -= 2 * HC;
    if (tid == 0) *counter = 0;
}

// ---- ELL build: one atomic pass over edges ----

__global__ void fill_ell(const int* __restrict__ ei, int* cnt, u16* __restrict__ ell, int E) {
    int tid = blockIdx.x * blockDim.x + threadIdx.x;
    if (tid < E) {
        int src = ei[tid];
        int dst = ei[E + tid];
        int pos = atomicAdd(&cnt[dst], 1);
        if (pos < ELL_CAP) ell[(size_t)dst * ELL_CAP + pos] = (u16)src;  // guard: memory safety only
    }
}

// ---------------- bf16 MFMA GEMM + fused attention coefficients ----------------
// H[M,256] = A[M,K] @ Wt^T; blockIdx.y selects a PAIR of heads (128 cols).

__global__ __launch_bounds__(256) void gemm_bf16(
        const bf16s* __restrict__ A, const bf16s* __restrict__ Wt,
        bf16s* __restrict__ Hout,
        const float* __restrict__ a_src, const float* __restrict__ a_dst,
        float* __restrict__ asb, float* __restrict__ adb,
        int M, int K) {
    __shared__ bf16s As[128][72];
    __shared__ bf16s Bs[128][72];
    int tid = threadIdx.x;
    int wave = tid >> 6, lane = tid & 63;
    int row0 = blockIdx.x * 128;
    int head2 = blockIdx.y;          // pair index: cols [head2*128, head2*128+128)
    int col0 = head2 * 128;
    int lr = lane & 15, lk = lane >> 4;

    f32x4 acc[2][8];
    #pragma unroll
    for (int i = 0; i < 2; i++)
        #pragma unroll
        for (int j = 0; j < 8; j++)
            acc[i][j] = (f32x4){0.f, 0.f, 0.f, 0.f};

    for (int k0 = 0; k0 < K; k0 += 64) {
        #pragma unroll
        for (int i = 0; i < 4; i++) {
            int idx = tid + i * 256;
            int r = idx >> 3, ch = idx & 7;
            int gr = row0 + r;
            bf16x8 v = {};
            if (gr < M) v = *reinterpret_cast<const bf16x8*>(A + (size_t)gr * K + k0 + ch * 8);
            *reinterpret_cast<bf16x8*>(&As[r][ch * 8]) = v;
        }
        #pragma unroll
        for (int i = 0; i < 4; i++) {
            int idx = tid + i * 256;
            int r = idx >> 3, ch = idx & 7;
            bf16x8 v = *reinterpret_cast<const bf16x8*>(Wt + (size_t)(col0 + r) * K + k0 + ch * 8);
            *reinterpret_cast<bf16x8*>(&Bs[r][ch * 8]) = v;
        }
        __syncthreads();
        #pragma unroll
        for (int ks = 0; ks < 2; ks++) {
            bf16x8 bfr[8];
            #pragma unroll
            for (int j = 0; j < 8; j++)
                bfr[j] = *reinterpret_cast<const bf16x8*>(&Bs[j * 16 + lr][ks * 32 + lk * 8]);
            #pragma unroll
            for (int i = 0; i < 2; i++) {
                bf16x8 afr = *reinterpret_cast<const bf16x8*>(&As[wave * 32 + i * 16 + lr][ks * 32 + lk * 8]);
                #pragma unroll
                for (int j = 0; j < 8; j++)
                    acc[i][j] = __builtin_amdgcn_mfma_f32_16x16x32_bf16(afr, bfr[j], acc[i][j], 0, 0, 0);
            }
        }
        __syncthreads();
    }

    // store H (C/D layout: col = lane&15, row = (lane>>4)*4 + q)
    #pragma unroll
    for (int i = 0; i < 2; i++) {
        #pragma unroll
        for (int q = 0; q < 4; q++) {
            int r = row0 + wave * 32 + i * 16 + lk * 4 + q;
            if (r < M) {
                #pragma unroll
                for (int j = 0; j < 8; j++) {
                    int c = col0 + j * 16 + lr;
                    Hout[(size_t)r * HC + c] = f2bs(acc[i][j][q]);
                }
            }
        }
    }

    // fused attn coefficients for BOTH heads of this pair
    float asv[8], adv[8];
    #pragma unroll
    for (int j = 0; j < 8; j++) {
        asv[j] = a_src[col0 + j * 16 + lr];
        adv[j] = a_dst[col0 + j * 16 + lr];
    }
    #pragma unroll
    for (int i = 0; i < 2; i++) {
        #pragma unroll
        for (int q = 0; q < 4; q++) {
            float ps0 = acc[i][0][q] * asv[0] + acc[i][1][q] * asv[1] + acc[i][2][q] * asv[2] + acc[i][3][q] * asv[3];
            float pd0 = acc[i][0][q] * adv[0] + acc[i][1][q] * adv[1] + acc[i][2][q] * adv[2] + acc[i][3][q] * adv[3];
            float ps1 = acc[i][4][q] * asv[4] + acc[i][5][q] * asv[5] + acc[i][6][q] * asv[6] + acc[i][7][q] * asv[7];
            float pd1 = acc[i][4][q] * adv[4] + acc[i][5][q] * adv[5] + acc[i][6][q] * adv[6] + acc[i][7][q] * adv[7];
            #pragma unroll
            for (int off = 1; off < 16; off <<= 1) {
                ps0 += __shfl_xor(ps0, off);
                pd0 += __shfl_xor(pd0, off);
                ps1 += __shfl_xor(ps1, off);
                pd1 += __shfl_xor(pd1, off);
            }
            int r = row0 + wave * 32 + i * 16 + lk * 4 + q;
            if (lr == 0 && r < M) {
                asb[r * HEADS + head2 * 2 + 0] = ps0;
                adb[r * HEADS + head2 * 2 + 0] = pd0;
                asb[r * HEADS + head2 * 2 + 1] = ps1;
                adb[r * HEADS + head2 * 2 + 1] = pd1;
            }
        }
    }
}

// ---------------- GAT aggregation v6: single-pass (sum & weighted-sum together), no LDS ----------------
// out = (sum_j e_j * h_j) / (sum_j e_j) + bias, with e = exp(lrelu(as+ad)) (no max-shift; e is O(1)).

__device__ __forceinline__ float lrelu(float x) { return x > 0.f ? x : NEG_SLOPE * x; }

template<int MODE>
__global__ __launch_bounds__(256) void gat_aggregate(
        const bf16s* __restrict__ hfeat,
        const float* __restrict__ asb, const float* __restrict__ adb,
        const int* __restrict__ cnt, const u16* __restrict__ ell,
        const float* __restrict__ bias,
        float* __restrict__ out) {
    int wid = threadIdx.x >> 6, lane = threadIdx.x & 63;
    int d = blockIdx.x * 4 + wid;         // grid exact: 4 waves/block
    int deg = min(cnt[d], ELL_CAP);
    const u16* row = ell + (size_t)d * ELL_CAP;

    int half = lane >> 5;
    int cl = lane & 31;
    int hsel = cl >> 3;
    float adh = adb[d * HEADS + hsel];    // per-lane head offset (broadcast among 8 lanes)

    // single pass: 2 edges per half-wave in flight (A/B accumulator sets)
    float sa = 0.f, sb = 0.f;
    float a0 = 0.f, a1 = 0.f, a2 = 0.f, a3 = 0.f, a4 = 0.f, a5 = 0.f, a6 = 0.f, a7 = 0.f;
    float b0 = 0.f, b1 = 0.f, b2 = 0.f, b3 = 0.f, b4 = 0.f, b5 = 0.f, b6 = 0.f, b7 = 0.f;

    int nfull = deg & ~3;
    for (int j = 0; j < nfull; j += 4) {
        int sA = row[j + half];
        int sB = row[j + 2 + half];
        float eA = __expf(lrelu(asb[(size_t)sA * HEADS + hsel] + adh));
        float eB = __expf(lrelu(asb[(size_t)sB * HEADS + hsel] + adh));
        const bf16x8 vA = *reinterpret_cast<const bf16x8*>(hfeat + (size_t)sA * HC + cl * 8);
        const bf16x8 vB = *reinterpret_cast<const bf16x8*>(hfeat + (size_t)sB * HC + cl * 8);
        sa += eA; sb += eB;
        a0 += eA * bs2f(vA[0]); a1 += eA * bs2f(vA[1]);
        a2 += eA * bs2f(vA[2]); a3 += eA * bs2f(vA[3]);
        a4 += eA * bs2f(vA[4]); a5 += eA * bs2f(vA[5]);
        a6 += eA * bs2f(vA[6]); a7 += eA * bs2f(vA[7]);
        b0 += eB * bs2f(vB[0]); b1 += eB * bs2f(vB[1]);
        b2 += eB * bs2f(vB[2]); b3 += eB * bs2f(vB[3]);
        b4 += eB * bs2f(vB[4]); b5 += eB * bs2f(vB[5]);
        b6 += eB * bs2f(vB[6]); b7 += eB * bs2f(vB[7]);
    }
    // tail (0..3 edges): half 0 even offsets, half 1 odd
    for (int j = nfull + half; j < deg; j += 2) {
        int s = row[j];
        float e = __expf(lrelu(asb[(size_t)s * HEADS + hsel] + adh));
        const bf16x8 v = *reinterpret_cast<const bf16x8*>(hfeat + (size_t)s * HC + cl * 8);
        sa += e;
        a0 += e * bs2f(v[0]); a1 += e * bs2f(v[1]);
        a2 += e * bs2f(v[2]); a3 += e * bs2f(v[3]);
        a4 += e * bs2f(v[4]); a5 += e * bs2f(v[5]);
        a6 += e * bs2f(v[6]); a7 += e * bs2f(v[7]);
    }
    float ssum = sa + sb;
    ssum += __shfl_xor(ssum, 32);
    float av0 = a0 + b0, av1 = a1 + b1, av2 = a2 + b2, av3 = a3 + b3;
    float av4 = a4 + b4, av5 = a5 + b5, av6 = a6 + b6, av7 = a7 + b7;
    av0 += __shfl_xor(av0, 32); av1 += __shfl_xor(av1, 32);
    av2 += __shfl_xor(av2, 32); av3 += __shfl_xor(av3, 32);
    av4 += __shfl_xor(av4, 32); av5 += __shfl_xor(av5, 32);
    av6 += __shfl_xor(av6, 32); av7 += __shfl_xor(av7, 32);
    float rdh = 1.f / (ssum + 1e-16f);
    av0 *= rdh; av1 *= rdh; av2 *= rdh; av3 *= rdh;
    av4 *= rdh; av5 *= rdh; av6 *= rdh; av7 *= rdh;

    if constexpr (MODE == 0) {
        if (half == 0) {
            const float4 bb0 = *reinterpret_cast<const float4*>(bias + cl * 8);
            const float4 bb1 = *reinterpret_cast<const float4*>(bias + cl * 8 + 4);
            av0 += bb0.x; av1 += bb0.y; av2 += bb0.z; av3 += bb0.w;
            av4 += bb1.x; av5 += bb1.y; av6 += bb1.z; av7 += bb1.w;
            float4 o0; o0.x = av0; o0.y = av1; o0.z = av2; o0.w = av3;
            float4 o1; o1.x = av4; o1.y = av5; o1.z = av6; o1.w = av7;
            *reinterpret_cast<float4*>(out + (size_t)d * HC + cl * 8) = o0;
            *reinterpret_cast<float4*>(out + (size_t)d * HC + cl * 8 + 4) = o1;
        }
    } else {
        // head mean over lane bits 3,4 (the 4 heads); av* already normalized per-head
        float h0 = av0 + __shfl_xor(av0, 8); h0 += __shfl_xor(h0, 16);
        float h1 = av1 + __shfl_xor(av1, 8); h1 += __shfl_xor(h1, 16);
        float h2 = av2 + __shfl_xor(av2, 8); h2 += __shfl_xor(h2, 16);
        float h3 = av3 + __shfl_xor(av3, 8); h3 += __shfl_xor(h3, 16);
        float h4 = av4 + __shfl_xor(av4, 8); h4 += __shfl_xor(h4, 16);
        float h5 = av5 + __shfl_xor(av5, 8); h5 += __shfl_xor(h5, 16);
        float h6 = av6 + __shfl_xor(av6, 8); h6 += __shfl_xor(h6, 16);
        float h7 = av7 + __shfl_xor(av7, 8); h7 += __shfl_xor(h7, 16);
        if (half == 0 && cl < 8) {
            int c = cl * 8;
            float4 o0, o1;
            o0.x = 0.25f * h0 + bias[c + 0]; o0.y = 0.25f * h1 + bias[c + 1];
            o0.z = 0.25f * h2 + bias[c + 2]; o0.w = 0.25f * h3 + bias[c + 3];
            o1.x = 0.25f * h4 + bias[c + 4]; o1.y = 0.25f * h5 + bias[c + 5];
            o1.z = 0.25f * h6 + bias[c + 6]; o1.w = 0.25f * h7 + bias[c + 7];
            *reinterpret_cast<float4*>(out + (size_t)d * HID + c) = o0;
            *reinterpret_cast<float4*>(out + (size_t)d * HID + c + 4) = o1;
        }
    }
}

// ---------------- BatchNorm: stats + finalize fused (last-block-done) ----------------

__global__ void bn_stats_fin(const float* __restrict__ x, float* colsum, float* colsq,
                             const float* __restrict__ g, const float* __restrict__ be,
                             float* scale, float* shift, int* counter, int n) {
    __shared__ int lastFlag;
    int col = threadIdx.x;  // 256 threads
    float s = 0.f, q = 0.f;
    for (int r = blockIdx.x; r < n; r += gridDim.x) {
        float v = x[(size_t)r * HC + col];
        s += v;
        q += v * v;
    }
    atomicAdd(&colsum[col], s);
    atomicAdd(&colsq[col], q);
    __syncthreads();
    if (threadIdx.x == 0) {
        __threadfence();
        int prev = atomicAdd(counter, 1);
        lastFlag = (prev == (int)gridDim.x - 1) ? 1 : 0;
    }
    __syncthreads();
    if (lastFlag) {
        __threadfence();
        float cs = ((volatile float*)colsum)[col];
        float cq = ((volatile float*)colsq)[col];
        float mu = cs / (float)n;
        float var = cq / (float)n - mu * mu;
        float sc = g[col] * rsqrtf(var + BN_EPS);
        scale[col] = sc;
        shift[col] = be[col] - mu * sc;
        colsum[col] = 0.f;                 // re-zero for next layer
        colsq[col] = 0.f;
        if (threadIdx.x == 0) *counter = 0;
    }
}

__global__ void bn_apply_elu(const float* __restrict__ x,
                             const float* __restrict__ scale, const float* __restrict__ shift,
                             float* __restrict__ xs_out, bf16s* __restrict__ act, int n) {
    int col = threadIdx.x;  // 256
    float sc = scale[col], sh = shift[col];
    for (int r = blockIdx.x; r < n; r += gridDim.x) {
        float v = x[(size_t)r * HC + col];
        float y = v * sc + sh;
        xs_out[(size_t)r * HC + col] = y;
        float e = y > 0.f ? y : __expf(y) - 1.f;
        act[(size_t)r * HC + col] = f2bs(e);
    }
}

// ---------------- pool + final linear: one block per graph ----------------

__global__ __launch_bounds__(256) void pool_final(
        const float* __restrict__ xs2, const int* __restrict__ batch,
        const float* __restrict__ Wlin, const float* __restrict__ blin,
        float* __restrict__ pooled_out, float* __restrict__ out_final) {
    __shared__ float red[4][HID];
    int g = blockIdx.x;
    int tid = threadIdx.x;
    int w = tid >> 6, lane = tid & 63;

    int lo = 0, hi = N_NODES;
    while (lo < hi) { int mid = (lo + hi) >> 1; if (batch[mid] < g) lo = mid + 1; else hi = mid; }
    int a = lo;
    lo = 0; hi = N_NODES;
    while (lo < hi) { int mid = (lo + hi) >> 1; if (batch[mid] < g + 1) lo = mid + 1; else hi = mid; }
    int b = lo;

    float acc = 0.f;
    for (int n = a + w; n < b; n += 4) acc += xs2[(size_t)n * HID + lane];
    red[w][lane] = acc;
    __syncthreads();

    if (w == 0) {
        float pooled = (red[0][lane] + red[1][lane] + red[2][lane] + red[3][lane])
                       / fmaxf((float)(b - a), 1.f);
        pooled_out[g * HID + lane] = pooled;
        #pragma unroll
        for (int o = 0; o < OUT_DIM; o++) {
            float p = pooled * Wlin[lane * OUT_DIM + o];
            #pragma unroll
            for (int off = 32; off > 0; off >>= 1) p += __shfl_xor(p, off);
            if (lane == 0) out_final[g * OUT_DIM + o] = p + blin[o];
        }
    }
}

// ---------------- host side ----------------

extern "C" void kernel_launch(void* const* d_in, const int* in_sizes, int n_in,
                              void* d_out, int out_size, void* d_ws, size_t ws_size,
                              hipStream_t stream) {
    const float* x     = (const float*)d_in[0];
    const int*   ei    = (const int*)d_in[1];   // [2,E]
    const int*   batch = (const int*)d_in[2];
    const float* W1  = (const float*)d_in[3];
    const float* as1 = (const float*)d_in[4];
    const float* ad1 = (const float*)d_in[5];
    const float* b1  = (const float*)d_in[6];
    const float* g1  = (const float*)d_in[7];
    const float* be1 = (const float*)d_in[8];
    const float* W2  = (const float*)d_in[9];
    const float* as2 = (const float*)d_in[10];
    const float* ad2 = (const float*)d_in[11];
    const float* b2  = (const float*)d_in[12];
    const float* g2  = (const float*)d_in[13];
    const float* be2 = (const float*)d_in[14];
    const float* W3  = (const float*)d_in[15];
    const float* as3 = (const float*)d_in[16];
    const float* ad3 = (const float*)d_in[17];
    const float* b3  = (const float*)d_in[18];
    const float* Wlin = (const float*)d_in[19];
    const float* blin = (const float*)d_in[20];

    // output regions
    float* out_final = (float*)d_out;                 // [128,10]
    float* xs0 = out_final + NUM_GRAPHS * OUT_DIM;    // [N,256]
    float* xs1 = xs0 + (size_t)N_NODES * HC;          // [N,256]
    float* xs2 = xs1 + (size_t)N_NODES * HC;          // [N,64]
    float* pooled_out = xs2 + (size_t)N_NODES * HID;  // [128,64]

    // workspace carve
    char* p = (char*)d_ws;
    auto alloc = [&](size_t bytes) { char* r = p; p += (bytes + 255) & ~(size_t)255; return (void*)r; };
    bf16s* hfeat  = (bf16s*)alloc((size_t)N_NODES * HC * 2);
    bf16s* actC   = (bf16s*)alloc((size_t)N_NODES * HC * 2);
    bf16s* xb     = (bf16s*)alloc((size_t)N_NODES * F_IN * 2);
    float* gatB   = (float*)alloc((size_t)N_NODES * HC * 4);
    bf16s* Wt1    = (bf16s*)alloc((size_t)HC * F_IN * 2);
    bf16s* Wt2    = (bf16s*)alloc((size_t)HC * HC * 2);
    bf16s* Wt3    = (bf16s*)alloc((size_t)HC * HC * 2);
    float* asb    = (float*)alloc((size_t)N_NODES * HEADS * 4);
    float* adb    = (float*)alloc((size_t)N_NODES * HEADS * 4);
    int*   cnt    = (int*)alloc((size_t)N_NODES * 4);
    u16*   ell    = (u16*)alloc((size_t)N_NODES * ELL_CAP * 2);   // 5.12 MB
    float* colstats = (float*)alloc(2 * HC * 4);
    float* colsum = colstats;
    float* colsq  = colstats + HC;
    float* scale  = (float*)alloc(HC * 4);
    float* shift  = (float*)alloc(HC * 4);
    int*   counter = (int*)alloc(256);

    const int PREP_TOT = CONV_N + HC * F_IN + 2 * HC * HC + N_NODES + 2 * HC + 1;

    // ---- fused prep + ELL build ----
    prep_all<<<(PREP_TOT + 255) / 256, 256, 0, stream>>>(x, xb, W1, W2, W3, Wt1, Wt2, Wt3,
                                                         cnt, ell, colstats, counter);
    fill_ell<<<(N_EDGES + 255) / 256, 256, 0, stream>>>(ei, cnt, ell, N_EDGES);

    int agg_blocks = N_NODES / 4;   // exactly 4 waves/block
    dim3 ggrid((N_NODES + 127) / 128, HEADS / 2);   // head PAIRS

    // ---- layer 1 ----
    {
        gemm_bf16<<<ggrid, 256, 0, stream>>>(xb, Wt1, hfeat, as1, ad1, asb, adb, N_NODES, F_IN);
        gat_aggregate<0><<<agg_blocks, 256, 0, stream>>>(hfeat, asb, adb, cnt, ell, b1, gatB);
        bn_stats_fin<<<512, 256, 0, stream>>>(gatB, colsum, colsq, g1, be1, scale, shift, counter, N_NODES);
        bn_apply_elu<<<2048, 256, 0, stream>>>(gatB, scale, shift, xs0, actC, N_NODES);
    }
    // ---- layer 2 ----
    {
        gemm_bf16<<<ggrid, 256, 0, stream>>>(actC, Wt2, hfeat, as2, ad2, asb, adb, N_NODES, HC);
        gat_aggregate<0><<<agg_blocks, 256, 0, stream>>>(hfeat, asb, adb, cnt, ell, b2, gatB);
        bn_stats_fin<<<512, 256, 0, stream>>>(gatB, colsum, colsq, g2, be2, scale, shift, counter, N_NODES);
        bn_apply_elu<<<2048, 256, 0, stream>>>(gatB, scale, shift, xs1, actC, N_NODES);
    }
    // ---- layer 3 ----
    {
        gemm_bf16<<<ggrid, 256, 0, stream>>>(actC, Wt3, hfeat, as3, ad3, asb, adb, N_NODES, HC);
        gat_aggregate<1><<<agg_blocks, 256, 0, stream>>>(hfeat, asb, adb, cnt, ell, b3, xs2);
    }
    // ---- pool + final linear ----
    pool_final<<<NUM_GRAPHS, 256, 0, stream>>>(xs2, batch, Wlin, blin, pooled_out, out_final);
}

// Round 13
// 292.315 us; speedup vs baseline: 1.0576x; 1.0576x over previous
//
#include <hip/hip_runtime.h>
#include <hip/hip_bf16.h>
#include <math.h>

#define N_NODES 20000
#define N_EDGES 640000
#define F_IN 128
#define HID 64
#define HEADS 4
#define HC 256      // HEADS*HID
#define OUT_DIM 10
#define NUM_GRAPHS 128
#define NEG_SLOPE 0.2f
#define BN_EPS 1e-5f
#define CONV_N (N_NODES * F_IN / 4)
#define ELL_CAP 128       // max degree+1; deg ~ Poisson(32), P(deg>=128) < 1e-30
#define GEMM_BX 157       // ceil(20000/128)
#define FILL_BLOCKS 2500  // ceil(640000/256)

typedef short bf16s;
typedef unsigned short u16;
using bf16x8 = __attribute__((ext_vector_type(8))) short;
using bf16x4 = __attribute__((ext_vector_type(4))) short;
using f32x4 = __attribute__((ext_vector_type(4))) float;

__device__ __forceinline__ float bs2f(short s) {
    unsigned int u = ((unsigned int)(unsigned short)s) << 16;
    return __builtin_bit_cast(float, u);
}
__device__ __forceinline__ short f2bs(float f) {
    unsigned int u = __builtin_bit_cast(unsigned int, f);
    unsigned int r = u + 0x7FFFu + ((u >> 16) & 1u);
    return (short)(r >> 16);
}

// ---- fused prep: x->bf16, 3x W transpose, cnt=1 + self-loop slot, colstats=0, counter=0 ----

__global__ void prep_all(const float* __restrict__ x, bf16s* __restrict__ xb,
                         const float* __restrict__ W1, const float* __restrict__ W2,
                         const float* __restrict__ W3,
                         bf16s* __restrict__ Wt1, bf16s* __restrict__ Wt2,
                         bf16s* __restrict__ Wt3,
                         int* __restrict__ cnt, u16* __restrict__ ell,
                         float* __restrict__ colstats, int* __restrict__ counter) {
    int tid = blockIdx.x * blockDim.x + threadIdx.x;
    if (tid < CONV_N) {
        float4 v = reinterpret_cast<const float4*>(x)[tid];
        bf16x4 o;
        o[0] = f2bs(v.x); o[1] = f2bs(v.y); o[2] = f2bs(v.z); o[3] = f2bs(v.w);
        reinterpret_cast<bf16x4*>(xb)[tid] = o;
        return;
    }
    tid -= CONV_N;
    if (tid < HC * F_IN) { int c = tid >> 7, k = tid & 127; Wt1[tid] = f2bs(W1[(size_t)k * HC + c]); return; }
    tid -= HC * F_IN;
    if (tid < HC * HC) { int c = tid >> 8, k = tid & 255; Wt2[tid] = f2bs(W2[(size_t)k * HC + c]); return; }
    tid -= HC * HC;
    if (tid < HC * HC) { int c = tid >> 8, k = tid & 255; Wt3[tid] = f2bs(W3[(size_t)k * HC + c]); return; }
    tid -= HC * HC;
    if (tid < N_NODES) {   // self-loop pre-planted at slot 0
        cnt[tid] = 1;
        ell[(size_t)tid * ELL_CAP] = (u16)tid;
        return;
    }
    tid -= N_NODES;
    if (tid < 2 * HC) { colstats[tid] = 0.f; return; }
    tid -= 2 * HC;
    if (tid == 0) *counter = 0;
}

// ---------------- GEMM core (device fn): 128 rows x 128 cols (head pair) ----------------

__device__ __forceinline__ void gemm_core(
        bf16s (*As)[72], bf16s (*Bs)[72],
        int bx, int head2,
        const bf16s* __restrict__ A, const bf16s* __restrict__ Wt,
        bf16s* __restrict__ Hout,
        const float* __restrict__ a_src, const float* __restrict__ a_dst,
        float* __restrict__ asb, float* __restrict__ adb,
        int M, int K) {
    int tid = threadIdx.x;
    int wave = tid >> 6, lane = tid & 63;
    int row0 = bx * 128;
    int col0 = head2 * 128;
    int lr = lane & 15, lk = lane >> 4;

    f32x4 acc[2][8];
    #pragma unroll
    for (int i = 0; i < 2; i++)
        #pragma unroll
        for (int j = 0; j < 8; j++)
            acc[i][j] = (f32x4){0.f, 0.f, 0.f, 0.f};

    for (int k0 = 0; k0 < K; k0 += 64) {
        #pragma unroll
        for (int i = 0; i < 4; i++) {
            int idx = tid + i * 256;
            int r = idx >> 3, ch = idx & 7;
            int gr = row0 + r;
            bf16x8 v = {};
            if (gr < M) v = *reinterpret_cast<const bf16x8*>(A + (size_t)gr * K + k0 + ch * 8);
            *reinterpret_cast<bf16x8*>(&As[r][ch * 8]) = v;
        }
        #pragma unroll
        for (int i = 0; i < 4; i++) {
            int idx = tid + i * 256;
            int r = idx >> 3, ch = idx & 7;
            bf16x8 v = *reinterpret_cast<const bf16x8*>(Wt + (size_t)(col0 + r) * K + k0 + ch * 8);
            *reinterpret_cast<bf16x8*>(&Bs[r][ch * 8]) = v;
        }
        __syncthreads();
        #pragma unroll
        for (int ks = 0; ks < 2; ks++) {
            bf16x8 bfr[8];
            #pragma unroll
            for (int j = 0; j < 8; j++)
                bfr[j] = *reinterpret_cast<const bf16x8*>(&Bs[j * 16 + lr][ks * 32 + lk * 8]);
            #pragma unroll
            for (int i = 0; i < 2; i++) {
                bf16x8 afr = *reinterpret_cast<const bf16x8*>(&As[wave * 32 + i * 16 + lr][ks * 32 + lk * 8]);
                #pragma unroll
                for (int j = 0; j < 8; j++)
                    acc[i][j] = __builtin_amdgcn_mfma_f32_16x16x32_bf16(afr, bfr[j], acc[i][j], 0, 0, 0);
            }
        }
        __syncthreads();
    }

    // store H (C/D layout: col = lane&15, row = (lane>>4)*4 + q)
    #pragma unroll
    for (int i = 0; i < 2; i++) {
        #pragma unroll
        for (int q = 0; q < 4; q++) {
            int r = row0 + wave * 32 + i * 16 + lk * 4 + q;
            if (r < M) {
                #pragma unroll
                for (int j = 0; j < 8; j++) {
                    int c = col0 + j * 16 + lr;
                    Hout[(size_t)r * HC + c] = f2bs(acc[i][j][q]);
                }
            }
        }
    }

    // fused attn coefficients for BOTH heads of this pair
    float asv[8], adv[8];
    #pragma unroll
    for (int j = 0; j < 8; j++) {
        asv[j] = a_src[col0 + j * 16 + lr];
        adv[j] = a_dst[col0 + j * 16 + lr];
    }
    #pragma unroll
    for (int i = 0; i < 2; i++) {
        #pragma unroll
        for (int q = 0; q < 4; q++) {
            float ps0 = acc[i][0][q] * asv[0] + acc[i][1][q] * asv[1] + acc[i][2][q] * asv[2] + acc[i][3][q] * asv[3];
            float pd0 = acc[i][0][q] * adv[0] + acc[i][1][q] * adv[1] + acc[i][2][q] * adv[2] + acc[i][3][q] * adv[3];
            float ps1 = acc[i][4][q] * asv[4] + acc[i][5][q] * asv[5] + acc[i][6][q] * asv[6] + acc[i][7][q] * asv[7];
            float pd1 = acc[i][4][q] * adv[4] + acc[i][5][q] * adv[5] + acc[i][6][q] * adv[6] + acc[i][7][q] * adv[7];
            #pragma unroll
            for (int off = 1; off < 16; off <<= 1) {
                ps0 += __shfl_xor(ps0, off);
                pd0 += __shfl_xor(pd0, off);
                ps1 += __shfl_xor(ps1, off);
                pd1 += __shfl_xor(pd1, off);
            }
            int r = row0 + wave * 32 + i * 16 + lk * 4 + q;
            if (lr == 0 && r < M) {
                asb[r * HEADS + head2 * 2 + 0] = ps0;
                adb[r * HEADS + head2 * 2 + 0] = pd0;
                asb[r * HEADS + head2 * 2 + 1] = ps1;
                adb[r * HEADS + head2 * 2 + 1] = pd1;
            }
        }
    }
}

// standalone GEMM kernel (layers 2 and 3)
__global__ __launch_bounds__(256) void gemm_bf16(
        const bf16s* __restrict__ A, const bf16s* __restrict__ Wt,
        bf16s* __restrict__ Hout,
        const float* __restrict__ a_src, const float* __restrict__ a_dst,
        float* __restrict__ asb, float* __restrict__ adb,
        int M, int K) {
    __shared__ bf16s As[128][72];
    __shared__ bf16s Bs[128][72];
    gemm_core(As, Bs, blockIdx.x, blockIdx.y, A, Wt, Hout, a_src, a_dst, asb, adb, M, K);
}

// fat kernel: ELL build (latency-bound) overlapped with layer-1 GEMM (compute-bound)
__global__ __launch_bounds__(256) void gemm1_fill(
        const bf16s* __restrict__ A, const bf16s* __restrict__ Wt,
        bf16s* __restrict__ Hout,
        const float* __restrict__ a_src, const float* __restrict__ a_dst,
        float* __restrict__ asb, float* __restrict__ adb,
        const int* __restrict__ ei, int* cnt, u16* __restrict__ ell) {
    __shared__ bf16s As[128][72];
    __shared__ bf16s Bs[128][72];
    int bid = blockIdx.x;
    if (bid < FILL_BLOCKS) {
        int tid = bid * 256 + threadIdx.x;
        if (tid < N_EDGES) {
            int src = ei[tid];
            int dst = ei[N_EDGES + tid];
            int pos = atomicAdd(&cnt[dst], 1);
            if (pos < ELL_CAP) ell[(size_t)dst * ELL_CAP + pos] = (u16)src;  // guard: memory safety only
        }
    } else {
        int gb = bid - FILL_BLOCKS;   // 0 .. 2*GEMM_BX-1
        gemm_core(As, Bs, gb % GEMM_BX, gb / GEMM_BX, A, Wt, Hout, a_src, a_dst, asb, adb, N_NODES, F_IN);
    }
}

// ---------------- GAT aggregation v5: ELL rows (u16), two-pass, LDS stash ----------------

__device__ __forceinline__ float lrelu(float x) { return x > 0.f ? x : NEG_SLOPE * x; }

template<int MODE>
__global__ __launch_bounds__(256) void gat_aggregate(
        const bf16s* __restrict__ hfeat,
        const float* __restrict__ asb, const float* __restrict__ adb,
        const int* __restrict__ cnt, const u16* __restrict__ ell,
        const float* __restrict__ bias,
        float* __restrict__ out) {
    __shared__ float4 exps[4][ELL_CAP];   // 8 KB
    __shared__ int    srcs[4][ELL_CAP];   // 2 KB
    int wid = threadIdx.x >> 6, lane = threadIdx.x & 63;
    int d = blockIdx.x * 4 + wid;         // grid exact: 4 waves/block
    int deg = min(cnt[d], ELL_CAP);
    const u16* row = ell + (size_t)d * ELL_CAP;

    float adv0 = adb[d * HEADS + 0], adv1 = adb[d * HEADS + 1];
    float adv2 = adb[d * HEADS + 2], adv3 = adb[d * HEADS + 3];

    // ---- pass A: per-head sum of exp(e); stash exp + src in LDS (deg <= 128 always) ----
    float s0 = 0.f, s1 = 0.f, s2 = 0.f, s3 = 0.f;
    for (int j = lane; j < deg; j += 64) {
        int s = row[j];
        const float4 av = *reinterpret_cast<const float4*>(asb + (size_t)s * HEADS);
        float e0 = __expf(lrelu(av.x + adv0));
        float e1 = __expf(lrelu(av.y + adv1));
        float e2 = __expf(lrelu(av.z + adv2));
        float e3 = __expf(lrelu(av.w + adv3));
        float4 ev; ev.x = e0; ev.y = e1; ev.z = e2; ev.w = e3;
        exps[wid][j] = ev;
        srcs[wid][j] = s;
        s0 += e0; s1 += e1; s2 += e2; s3 += e3;
    }
    #pragma unroll
    for (int off = 32; off > 0; off >>= 1) {
        s0 += __shfl_xor(s0, off);
        s1 += __shfl_xor(s1, off);
        s2 += __shfl_xor(s2, off);
        s3 += __shfl_xor(s3, off);
    }
    float r0 = 1.f / (s0 + 1e-16f), r1 = 1.f / (s1 + 1e-16f);
    float r2 = 1.f / (s2 + 1e-16f), r3 = 1.f / (s3 + 1e-16f);

    // ---- pass B: weighted gather; 2 edges per half-wave in flight; all meta from LDS ----
    int half = lane >> 5;
    int cl = lane & 31;
    int hsel = cl >> 3;
    float rdh = (hsel == 0) ? r0 : (hsel == 1) ? r1 : (hsel == 2) ? r2 : r3;
    const float* expf_base = reinterpret_cast<const float*>(&exps[wid][0]);

    float a0 = 0.f, a1 = 0.f, a2 = 0.f, a3 = 0.f, a4 = 0.f, a5 = 0.f, a6 = 0.f, a7 = 0.f;
    float b0 = 0.f, b1 = 0.f, b2 = 0.f, b3 = 0.f, b4 = 0.f, b5 = 0.f, b6 = 0.f, b7 = 0.f;

    int nfull = deg & ~3;
    for (int j = 0; j < nfull; j += 4) {
        int iA = j + half;
        int iB = j + 2 + half;
        int sA = srcs[wid][iA];
        int sB = srcs[wid][iB];
        float alA = expf_base[iA * 4 + hsel] * rdh;
        float alB = expf_base[iB * 4 + hsel] * rdh;
        const bf16x8 vA = *reinterpret_cast<const bf16x8*>(hfeat + (size_t)sA * HC + cl * 8);
        const bf16x8 vB = *reinterpret_cast<const bf16x8*>(hfeat + (size_t)sB * HC + cl * 8);
        a0 += alA * bs2f(vA[0]); a1 += alA * bs2f(vA[1]);
        a2 += alA * bs2f(vA[2]); a3 += alA * bs2f(vA[3]);
        a4 += alA * bs2f(vA[4]); a5 += alA * bs2f(vA[5]);
        a6 += alA * bs2f(vA[6]); a7 += alA * bs2f(vA[7]);
        b0 += alB * bs2f(vB[0]); b1 += alB * bs2f(vB[1]);
        b2 += alB * bs2f(vB[2]); b3 += alB * bs2f(vB[3]);
        b4 += alB * bs2f(vB[4]); b5 += alB * bs2f(vB[5]);
        b6 += alB * bs2f(vB[6]); b7 += alB * bs2f(vB[7]);
    }
    // tail (0..3 edges): half 0 even offsets, half 1 odd
    for (int j = nfull + half; j < deg; j += 2) {
        int s = srcs[wid][j];
        float al = expf_base[j * 4 + hsel] * rdh;
        const bf16x8 v = *reinterpret_cast<const bf16x8*>(hfeat + (size_t)s * HC + cl * 8);
        a0 += al * bs2f(v[0]); a1 += al * bs2f(v[1]);
        a2 += al * bs2f(v[2]); a3 += al * bs2f(v[3]);
        a4 += al * bs2f(v[4]); a5 += al * bs2f(v[5]);
        a6 += al * bs2f(v[6]); a7 += al * bs2f(v[7]);
    }
    float av0 = a0 + b0, av1 = a1 + b1, av2 = a2 + b2, av3 = a3 + b3;
    float av4 = a4 + b4, av5 = a5 + b5, av6 = a6 + b6, av7 = a7 + b7;

    av0 += __shfl_xor(av0, 32); av1 += __shfl_xor(av1, 32);
    av2 += __shfl_xor(av2, 32); av3 += __shfl_xor(av3, 32);
    av4 += __shfl_xor(av4, 32); av5 += __shfl_xor(av5, 32);
    av6 += __shfl_xor(av6, 32); av7 += __shfl_xor(av7, 32);

    if constexpr (MODE == 0) {
        if (half == 0) {
            const float4 bb0 = *reinterpret_cast<const float4*>(bias + cl * 8);
            const float4 bb1 = *reinterpret_cast<const float4*>(bias + cl * 8 + 4);
            av0 += bb0.x; av1 += bb0.y; av2 += bb0.z; av3 += bb0.w;
            av4 += bb1.x; av5 += bb1.y; av6 += bb1.z; av7 += bb1.w;
            float4 o0; o0.x = av0; o0.y = av1; o0.z = av2; o0.w = av3;
            float4 o1; o1.x = av4; o1.y = av5; o1.z = av6; o1.w = av7;
            *reinterpret_cast<float4*>(out + (size_t)d * HC + cl * 8) = o0;
            *reinterpret_cast<float4*>(out + (size_t)d * HC + cl * 8 + 4) = o1;
        }
    } else {
        float h0 = av0 + __shfl_xor(av0, 8); h0 += __shfl_xor(h0, 16);
        float h1 = av1 + __shfl_xor(av1, 8); h1 += __shfl_xor(h1, 16);
        float h2 = av2 + __shfl_xor(av2, 8); h2 += __shfl_xor(h2, 16);
        float h3 = av3 + __shfl_xor(av3, 8); h3 += __shfl_xor(h3, 16);
        float h4 = av4 + __shfl_xor(av4, 8); h4 += __shfl_xor(h4, 16);
        float h5 = av5 + __shfl_xor(av5, 8); h5 += __shfl_xor(h5, 16);
        float h6 = av6 + __shfl_xor(av6, 8); h6 += __shfl_xor(h6, 16);
        float h7 = av7 + __shfl_xor(av7, 8); h7 += __shfl_xor(h7, 16);
        if (half == 0 && cl < 8) {
            int c = cl * 8;
            float4 o0, o1;
            o0.x = 0.25f * h0 + bias[c + 0]; o0.y = 0.25f * h1 + bias[c + 1];
            o0.z = 0.25f * h2 + bias[c + 2]; o0.w = 0.25f * h3 + bias[c + 3];
            o1.x = 0.25f * h4 + bias[c + 4]; o1.y = 0.25f * h5 + bias[c + 5];
            o1.z = 0.25f * h6 + bias[c + 6]; o1.w = 0.25f * h7 + bias[c + 7];
            *reinterpret_cast<float4*>(out + (size_t)d * HID + c) = o0;
            *reinterpret_cast<float4*>(out + (size_t)d * HID + c + 4) = o1;
        }
    }
}

// ---------------- BatchNorm: stats + finalize fused (last-block-done) ----------------

__global__ void bn_stats_fin(const float* __restrict__ x, float* colsum, float* colsq,
                             const float* __restrict__ g, const float* __restrict__ be,
                             float* scale, float* shift, int* counter, int n) {
    __shared__ int lastFlag;
    int col = threadIdx.x;  // 256 threads
    float s = 0.f, q = 0.f;
    for (int r = blockIdx.x; r < n; r += gridDim.x) {
        float v = x[(size_t)r * HC + col];
        s += v;
        q += v * v;
    }
    atomicAdd(&colsum[col], s);
    atomicAdd(&colsq[col], q);
    __syncthreads();
    if (threadIdx.x == 0) {
        __threadfence();
        int prev = atomicAdd(counter, 1);
        lastFlag = (prev == (int)gridDim.x - 1) ? 1 : 0;
    }
    __syncthreads();
    if (lastFlag) {
        __threadfence();
        float cs = ((volatile float*)colsum)[col];
        float cq = ((volatile float*)colsq)[col];
        float mu = cs / (float)n;
        float var = cq / (float)n - mu * mu;
        float sc = g[col] * rsqrtf(var + BN_EPS);
        scale[col] = sc;
        shift[col] = be[col] - mu * sc;
        colsum[col] = 0.f;                 // re-zero for next layer
        colsq[col] = 0.f;
        if (threadIdx.x == 0) *counter = 0;
    }
}

__global__ void bn_apply_elu(const float* __restrict__ x,
                             const float* __restrict__ scale, const float* __restrict__ shift,
                             float* __restrict__ xs_out, bf16s* __restrict__ act, int n) {
    int col = threadIdx.x;  // 256
    float sc = scale[col], sh = shift[col];
    for (int r = blockIdx.x; r < n; r += gridDim.x) {
        float v = x[(size_t)r * HC + col];
        float y = v * sc + sh;
        xs_out[(size_t)r * HC + col] = y;
        float e = y > 0.f ? y : __expf(y) - 1.f;
        act[(size_t)r * HC + col] = f2bs(e);
    }
}

// ---------------- pool + final linear: one block per graph ----------------

__global__ __launch_bounds__(256) void pool_final(
        const float* __restrict__ xs2, const int* __restrict__ batch,
        const float* __restrict__ Wlin, const float* __restrict__ blin,
        float* __restrict__ pooled_out, float* __restrict__ out_final) {
    __shared__ float red[4][HID];
    int g = blockIdx.x;
    int tid = threadIdx.x;
    int w = tid >> 6, lane = tid & 63;

    int lo = 0, hi = N_NODES;
    while (lo < hi) { int mid = (lo + hi) >> 1; if (batch[mid] < g) lo = mid + 1; else hi = mid; }
    int a = lo;
    lo = 0; hi = N_NODES;
    while (lo < hi) { int mid = (lo + hi) >> 1; if (batch[mid] < g + 1) lo = mid + 1; else hi = mid; }
    int b = lo;

    float acc = 0.f;
    for (int n = a + w; n < b; n += 4) acc += xs2[(size_t)n * HID + lane];
    red[w][lane] = acc;
    __syncthreads();

    if (w == 0) {
        float pooled = (red[0][lane] + red[1][lane] + red[2][lane] + red[3][lane])
                       / fmaxf((float)(b - a), 1.f);
        pooled_out[g * HID + lane] = pooled;
        #pragma unroll
        for (int o = 0; o < OUT_DIM; o++) {
            float p = pooled * Wlin[lane * OUT_DIM + o];
            #pragma unroll
            for (int off = 32; off > 0; off >>= 1) p += __shfl_xor(p, off);
            if (lane == 0) out_final[g * OUT_DIM + o] = p + blin[o];
        }
    }
}

// ---------------- host side ----------------

extern "C" void kernel_launch(void* const* d_in, const int* in_sizes, int n_in,
                              void* d_out, int out_size, void* d_ws, size_t ws_size,
                              hipStream_t stream) {
    const float* x     = (const float*)d_in[0];
    const int*   ei    = (const int*)d_in[1];   // [2,E]
    const int*   batch = (const int*)d_in[2];
    const float* W1  = (const float*)d_in[3];
    const float* as1 = (const float*)d_in[4];
    const float* ad1 = (const float*)d_in[5];
    const float* b1  = (const float*)d_in[6];
    const float* g1  = (const float*)d_in[7];
    const float* be1 = (const float*)d_in[8];
    const float* W2  = (const float*)d_in[9];
    const float* as2 = (const float*)d_in[10];
    const float* ad2 = (const float*)d_in[11];
    const float* b2  = (const float*)d_in[12];
    const float* g2  = (const float*)d_in[13];
    const float* be2 = (const float*)d_in[14];
    const float* W3  = (const float*)d_in[15];
    const float* as3 = (const float*)d_in[16];
    const float* ad3 = (const float*)d_in[17];
    const float* b3  = (const float*)d_in[18];
    const float* Wlin = (const float*)d_in[19];
    const float* blin = (const float*)d_in[20];

    // output regions
    float* out_final = (float*)d_out;                 // [128,10]
    float* xs0 = out_final + NUM_GRAPHS * OUT_DIM;    // [N,256]
    float* xs1 = xs0 + (size_t)N_NODES * HC;          // [N,256]
    float* xs2 = xs1 + (size_t)N_NODES * HC;          // [N,64]
    float* pooled_out = xs2 + (size_t)N_NODES * HID;  // [128,64]

    // workspace carve
    char* p = (char*)d_ws;
    auto alloc = [&](size_t bytes) { char* r = p; p += (bytes + 255) & ~(size_t)255; return (void*)r; };
    bf16s* hfeat  = (bf16s*)alloc((size_t)N_NODES * HC * 2);
    bf16s* actC   = (bf16s*)alloc((size_t)N_NODES * HC * 2);
    bf16s* xb     = (bf16s*)alloc((size_t)N_NODES * F_IN * 2);
    float* gatB   = (float*)alloc((size_t)N_NODES * HC * 4);
    bf16s* Wt1    = (bf16s*)alloc((size_t)HC * F_IN * 2);
    bf16s* Wt2    = (bf16s*)alloc((size_t)HC * HC * 2);
    bf16s* Wt3    = (bf16s*)alloc((size_t)HC * HC * 2);
    float* asb    = (float*)alloc((size_t)N_NODES * HEADS * 4);
    float* adb    = (float*)alloc((size_t)N_NODES * HEADS * 4);
    int*   cnt    = (int*)alloc((size_t)N_NODES * 4);
    u16*   ell    = (u16*)alloc((size_t)N_NODES * ELL_CAP * 2);   // 5.12 MB
    float* colstats = (float*)alloc(2 * HC * 4);
    float* colsum = colstats;
    float* colsq  = colstats + HC;
    float* scale  = (float*)alloc(HC * 4);
    float* shift  = (float*)alloc(HC * 4);
    int*   counter = (int*)alloc(256);

    const int PREP_TOT = CONV_N + HC * F_IN + 2 * HC * HC + N_NODES + 2 * HC + 1;

    // ---- fused prep ----
    prep_all<<<(PREP_TOT + 255) / 256, 256, 0, stream>>>(x, xb, W1, W2, W3, Wt1, Wt2, Wt3,
                                                         cnt, ell, colstats, counter);

    int agg_blocks = N_NODES / 4;   // exactly 4 waves/block
    dim3 ggrid(GEMM_BX, HEADS / 2); // head PAIRS

    // ---- layer 1 (GEMM fused with ELL build: independent work, one dispatch) ----
    {
        gemm1_fill<<<FILL_BLOCKS + GEMM_BX * 2, 256, 0, stream>>>(
            xb, Wt1, hfeat, as1, ad1, asb, adb, ei, cnt, ell);
        gat_aggregate<0><<<agg_blocks, 256, 0, stream>>>(hfeat, asb, adb, cnt, ell, b1, gatB);
        bn_stats_fin<<<512, 256, 0, stream>>>(gatB, colsum, colsq, g1, be1, scale, shift, counter, N_NODES);
        bn_apply_elu<<<2048, 256, 0, stream>>>(gatB, scale, shift, xs0, actC, N_NODES);
    }
    // ---- layer 2 ----
    {
        gemm_bf16<<<ggrid, 256, 0, stream>>>(actC, Wt2, hfeat, as2, ad2, asb, adb, N_NODES, HC);
        gat_aggregate<0><<<agg_blocks, 256, 0, stream>>>(hfeat, asb, adb, cnt, ell, b2, gatB);
        bn_stats_fin<<<512, 256, 0, stream>>>(gatB, colsum, colsq, g2, be2, scale, shift, counter, N_NODES);
        bn_apply_elu<<<2048, 256, 0, stream>>>(gatB, scale, shift, xs1, actC, N_NODES);
    }
    // ---- layer 3 ----
    {
        gemm_bf16<<<ggrid, 256, 0, stream>>>(actC, Wt3, hfeat, as3, ad3, asb, adb, N_NODES, HC);
        gat_aggregate<1><<<agg_blocks, 256, 0, stream>>>(hfeat, asb, adb, cnt, ell, b3, xs2);
    }
    // ---- pool + final linear ----
    pool_final<<<NUM_GRAPHS, 256, 0, stream>>>(xs2, batch, Wlin, blin, pooled_out, out_final);
}